// Round 17
// baseline (179.856 us; speedup 1.0000x reference)
//
#include <hip/hip_runtime.h>
#include <cstdint>
#include <cstddef>
#include <utility>

#define SS 512
#define TT 32
#define NB 256
#define KSTEPS 510   // SS-2
#define PQUADS 128   // pstore quads per batch (4 rows each)
#define BT_BASE 72   // blocks 0..31 vit, 32..63 fwd, 64..71 gold, 72..327 backtrace

// ---------- unroll helper (compile-time indices -> registers) ----------
template <typename F, size_t... Is>
__device__ __forceinline__ void unroll_impl(F&& f, std::index_sequence<Is...>) {
  (f(std::integral_constant<int, (int)Is>{}), ...);
}
template <int N, typename F>
__device__ __forceinline__ void unrollN(F&& f) {
  unroll_impl(f, std::make_index_sequence<N>{});
}

// butterfly xor D within each 32-lane group (one-time reductions only)
template <int D>
__device__ __forceinline__ float bfly32(float v) {
  return __int_as_float(__builtin_amdgcn_ds_swizzle(__float_as_int(v), (D << 10) | 0x1f));
}
template <int D>
__device__ __forceinline__ int bfly32i(int v) {
  return __builtin_amdgcn_ds_swizzle(v, (D << 10) | 0x1f);
}

__device__ __forceinline__ float max3f(float a, float b, float c) {
  return fmaxf(fmaxf(a, b), c);  // fuses to v_max3_f32; fmax exact in any grouping
}

// ---- cross-half combine, orientation-proof (r14-verified) ----
__device__ __forceinline__ float combine_max32(float m) {
#if __has_builtin(__builtin_amdgcn_permlane32_swap)
  auto r = __builtin_amdgcn_permlane32_swap(__float_as_uint(m), __float_as_uint(m), false, false);
  return fmaxf(__uint_as_float(r[0]), __uint_as_float(r[1]));
#else
  return fmaxf(m, __shfl_xor(m, 32, 64));
#endif
}
__device__ __forceinline__ float combine_sum32(float m) {
#if __has_builtin(__builtin_amdgcn_permlane32_swap)
  auto r = __builtin_amdgcn_permlane32_swap(__float_as_uint(m), __float_as_uint(m), false, false);
  return __uint_as_float(r[0]) + __uint_as_float(r[1]);
#else
  return m + __shfl_xor(m, 32, 64);
#endif
}

// ---------- mask dtype autodetect (bool may arrive as i32 / u8 / f32) ----------
__device__ __forceinline__ int mask_mode(const void* m) {
  int w0 = ((const int*)m)[0];
  if (w0 == 1) return 0;                // int32 0/1
  if (w0 == 0x3f800000) return 2;       // float32 1.0
  return 1;                             // uint8
}
__device__ __forceinline__ bool mask_at(const void* m, int idx, int mode) {
  if (mode == 0) return ((const int*)m)[idx] != 0;
  if (mode == 2) return ((const float*)m)[idx] != 0.0f;
  return ((const unsigned char*)m)[idx] != 0;
}

// per-wave sequence length (lane in [0,64)); result uniform (SGPR)
__device__ __forceinline__ int seq_length_lane(const void* mask, int b, int lane, int mode) {
  int cnt = 0;
  for (int s = lane; s < SS; s += 64) cnt += mask_at(mask, b * SS + s, mode) ? 1 : 0;
  for (int d = 1; d < 64; d <<= 1) cnt += __shfl_xor(cnt, d, 64);
  return __builtin_amdgcn_readfirstlane(cnt);
}

// ---------- fused kernel: vit / fwd / gold / backtrace, flag-synced ----------
// Producer->consumer: vit wave b sets flags[b] after release fence; backtrace
// block b spins on it. All 328 blocks are co-resident (<=3 blocks/CU by LDS,
// capacity 768), so spinning cannot starve producers (no deadlock).
__global__ __launch_bounds__(512, 1) void crf_fused_kernel(
    const float* __restrict__ feats, const float* __restrict__ trans,
    const void* __restrict__ mask, const int* __restrict__ tags,
    float* __restrict__ pstore, float* __restrict__ ws_fwd,
    float* __restrict__ ws_gold, int* __restrict__ ws_ptr,
    int* __restrict__ flags, int* __restrict__ cntp,
    float* __restrict__ out) {
  const int blk = blockIdx.x;
  const int tid = threadIdx.x;
  const int wave = tid >> 6;
  const int lane = tid & 63;
  const int j = lane & 31;   // owned tag
  const int h = lane >> 5;   // source half
  const int mode = mask_mode(mask);

  __shared__ __align__(16) float qlds[8][TT];        // per-wave chain slices
  __shared__ unsigned char bp[KSTEPS * TT];          // backtrace only
  __shared__ unsigned char path[KSTEPS * TT];
  __shared__ __align__(16) float pT[16][4][TT];
  __shared__ int entries[8];

  if (blk < 32) {
    // ================= VITERBI chains (8 per block, 1 per wave) =================
    const int b = blk * 8 + wave;
    const int steps = seq_length_lane(mask, b, lane, mode) - 2;
    const float* fb = feats + (size_t)b * (SS * TT) + j;
    float* pq = pstore + (size_t)b * (PQUADS * 128) + j * 4;

    float C[16];
    unrollN<16>([&](auto I) {
      constexpr int ii = I;
      C[ii] = trans[(h * 16 + ii) * TT + j];
    });

    float p = fb[TT];
    qlds[wave][j] = p;
    asm volatile("" ::: "memory");
    const float4* qvh = (const float4*)qlds[wave] + h * 4;

    float fA = fb[2 * TT], fB = fb[3 * TT], fC = fb[4 * TT];
    float h0 = p, h1 = 0.f, h2 = 0.f, h3 = 0.f;

    auto vstep = [&](int k, float& hslot) {
      float4 Q0 = qvh[0], Q1 = qvh[1], Q2 = qvh[2], Q3 = qvh[3];
      int r5 = k + 5; r5 = (r5 < SS) ? r5 : (SS - 1);
      float fD = fb[r5 * TT];
      float dd[16];
      unrollN<16>([&](auto I) { constexpr int ii = I; dd[ii] = fA + C[ii]; });  // fl(f+tr)
      float cur[16];  // fl(fl(f+tr) + p): reference op order
      cur[0] = Q0.x + dd[0];   cur[1] = Q0.y + dd[1];   cur[2] = Q0.z + dd[2];   cur[3] = Q0.w + dd[3];
      cur[4] = Q1.x + dd[4];   cur[5] = Q1.y + dd[5];   cur[6] = Q1.z + dd[6];   cur[7] = Q1.w + dd[7];
      cur[8] = Q2.x + dd[8];   cur[9] = Q2.y + dd[9];   cur[10] = Q2.z + dd[10]; cur[11] = Q2.w + dd[11];
      cur[12] = Q3.x + dd[12]; cur[13] = Q3.y + dd[13]; cur[14] = Q3.z + dd[14]; cur[15] = Q3.w + dd[15];
      float t0 = max3f(cur[0], cur[1], cur[2]);
      float t1 = max3f(cur[3], cur[4], cur[5]);
      float t2 = max3f(cur[6], cur[7], cur[8]);
      float t3 = max3f(cur[9], cur[10], cur[11]);
      float t4 = max3f(cur[12], cur[13], cur[14]);
      float m = fmaxf(max3f(t0, t1, t2), max3f(t3, t4, cur[15]));  // own-half max
      float pw = combine_max32(m);                 // full 32-source max (exact)
      p = pw;
      qlds[wave][j] = pw;
      asm volatile("" ::: "memory");
      hslot = pw;
      fA = fB; fB = fC; fC = fD;
    };

    auto flush = [&](int quad) {
      if (lane < 32) {
        float4 v; v.x = h0; v.y = h1; v.z = h2; v.w = h3;
        *(float4*)(pq + quad * 128) = v;
      }
    };

    int k = 0;
    for (; k + 4 <= steps; k += 4) {
      vstep(k, h1); vstep(k + 1, h2); vstep(k + 2, h3);
      flush(k >> 2);
      vstep(k + 3, h0);
    }
    if (k < steps) vstep(k, h1);
    if (k + 1 < steps) vstep(k + 1, h2);
    if (k + 2 < steps) vstep(k + 2, h3);
    flush(k >> 2);

    // pointer = first-max argmax over tags of final partition
    float v = p;
    int idx = j;
    unrollN<5>([&](auto D) {
      constexpr int d = 1 << D;
      float vo = bfly32<d>(v);
      int io = bfly32i<d>(idx);
      bool take = (vo > v) || ((vo == v) && (io < idx));
      v = take ? vo : v;
      idx = take ? io : idx;
    });
    if (lane == 0) ws_ptr[b] = idx;

    __threadfence();                               // release pstore + ws_ptr
    if (lane == 0) atomicExch(&flags[b], 1);

  } else if (blk < 64) {
    // ================= FORWARD chains (8 per block) =================
    const int b = (blk - 32) * 8 + wave;
    const int steps = seq_length_lane(mask, b, lane, mode) - 2;
    const float* fb = feats + (size_t)b * (SS * TT) + j;

    float E[16];
    unrollN<16>([&](auto I) {
      constexpr int ii = I;
      E[ii] = __expf(trans[(h * 16 + ii) * TT + j]);
    });

    float q = __expf(fb[TT]);
    int Eacc = 0;
    qlds[wave][j] = q;
    asm volatile("" ::: "memory");
    const float4* qvh = (const float4*)qlds[wave] + h * 4;

    float fA = fb[2 * TT], fB = fb[3 * TT], fC = fb[4 * TT];
    float ef = __expf(fA);

    auto fstep = [&](int k, bool resc) {
      float4 Q0 = qvh[0], Q1 = qvh[1], Q2 = qvh[2], Q3 = qvh[3];
      int r5 = k + 5; r5 = (r5 < SS) ? r5 : (SS - 1);
      float fD = fb[r5 * TT];
      float efN = __expf(fB);
      float a0, a1, a2, a3;
      a0 = Q0.x * E[0];  a1 = Q0.y * E[1];  a2 = Q0.z * E[2];  a3 = Q0.w * E[3];
      a0 = fmaf(Q1.x, E[4], a0);  a1 = fmaf(Q1.y, E[5], a1);  a2 = fmaf(Q1.z, E[6], a2);  a3 = fmaf(Q1.w, E[7], a3);
      a0 = fmaf(Q2.x, E[8], a0);  a1 = fmaf(Q2.y, E[9], a1);  a2 = fmaf(Q2.z, E[10], a2); a3 = fmaf(Q2.w, E[11], a3);
      a0 = fmaf(Q3.x, E[12], a0); a1 = fmaf(Q3.y, E[13], a1); a2 = fmaf(Q3.z, E[14], a2); a3 = fmaf(Q3.w, E[15], a3);
      float P = (a0 + a1) + (a2 + a3);
      float Pt = combine_sum32(P);
      q = ef * Pt;
      if (resc) {
        int qb = __builtin_amdgcn_readfirstlane(__float_as_int(q));
        int e = (qb >> 23) & 0xff;
        Eacc += e - 127;
        q *= __int_as_float((254 - e) << 23);
      }
      qlds[wave][j] = q;
      asm volatile("" ::: "memory");
      fA = fB; fB = fC; fC = fD; ef = efN;
    };

    int k = 0;
    for (; k + 4 <= steps; k += 4) {
      fstep(k, false); fstep(k + 1, false); fstep(k + 2, false); fstep(k + 3, true);
    }
    for (; k < steps; ++k) fstep(k, false);

    float s = q;
    unrollN<5>([&](auto D) { constexpr int d = 1 << D; s += bfly32<d>(s); });
    if (lane == 0) ws_fwd[b] = __logf(s) + (float)Eacc * 0.69314718056f;

    __threadfence();
    if (lane == 0) atomicAdd(cntp, 1);

  } else if (blk < BT_BASE) {
    // ================= GOLD SCORE (4 batches per wave) =================
    for (int bb = 0; bb < 4; ++bb) {
      const int b = (blk - 64) * 32 + wave * 4 + bb;
      float acc = 0.0f;
      for (int s = lane; s < SS; s += 64) {
        if (s == 0) continue;
        if (!mask_at(mask, b * SS + s, mode)) continue;
        int tg = tags[b * SS + s];
        if (tg == -100) tg = 0;
        float e = feats[((size_t)b * SS + s) * TT + tg];
        if (s >= 2) {
          int tp = tags[b * SS + s - 1];
          if (tp == -100) tp = 0;
          e += trans[tp * TT + tg];
        }
        acc += e;
      }
      for (int d = 1; d < 64; d <<= 1) acc += __shfl_xor(acc, d, 64);
      if (lane == 0) ws_gold[b] = acc;
    }
    __threadfence();
    if (tid == 0) { }
    if (lane == 0) atomicAdd(cntp, 4);

  } else {
    // ================= BACKTRACE (r15-verified body), flag-gated =================
    const int b = blk - BT_BASE;
    float* out_decode = out + 1 + NB;

    if (tid == 0) out[1 + b] = 0.0f;  // path_score = zeros(B)

    // wait for this batch's viterbi producer
    if (tid == 0) {
      while (atomicAdd(&flags[b], 0) == 0) __builtin_amdgcn_s_sleep(10);
    }
    __syncthreads();
    __threadfence();  // acquire: pstore + ws_ptr visible

    const int steps = seq_length_lane(mask, b, lane, mode) - 2;

    // ---- parallel bp recompute, quad-based
    {
      const int jj = tid & 31;
      const int g = tid >> 5;
      float Cc[TT];
      unrollN<TT>([&](auto I) { constexpr int ii = I; Cc[ii] = trans[ii * TT + jj]; });
      const float* pb = pstore + (size_t)b * (PQUADS * 128);
      const float* fbb = feats + (size_t)b * (SS * TT);
      for (int q = g; q < PQUADS; q += 16) {
        float4 V = *(const float4*)(pb + q * 128 + jj * 4);
        pT[g][0][jj] = V.x; pT[g][1][jj] = V.y; pT[g][2][jj] = V.z; pT[g][3][jj] = V.w;
        asm volatile("" ::: "memory");
        unrollN<4>([&](auto R) {
          constexpr int r = R;
          const int k = 4 * q + r;
          if (k < KSTEPS) {
            unsigned char bv = 0;
            if (k < steps) {
              const float4* pr = (const float4*)pT[g][r];
              float4 P0 = pr[0], P1 = pr[1], P2 = pr[2], P3 = pr[3];
              float4 P4 = pr[4], P5 = pr[5], P6 = pr[6], P7 = pr[7];
              float fj = fbb[(k + 2) * TT + jj];
              float cur[TT];
              cur[0]  = (fj + Cc[0])  + P0.x; cur[1]  = (fj + Cc[1])  + P0.y;
              cur[2]  = (fj + Cc[2])  + P0.z; cur[3]  = (fj + Cc[3])  + P0.w;
              cur[4]  = (fj + Cc[4])  + P1.x; cur[5]  = (fj + Cc[5])  + P1.y;
              cur[6]  = (fj + Cc[6])  + P1.z; cur[7]  = (fj + Cc[7])  + P1.w;
              cur[8]  = (fj + Cc[8])  + P2.x; cur[9]  = (fj + Cc[9])  + P2.y;
              cur[10] = (fj + Cc[10]) + P2.z; cur[11] = (fj + Cc[11]) + P2.w;
              cur[12] = (fj + Cc[12]) + P3.x; cur[13] = (fj + Cc[13]) + P3.y;
              cur[14] = (fj + Cc[14]) + P3.z; cur[15] = (fj + Cc[15]) + P3.w;
              cur[16] = (fj + Cc[16]) + P4.x; cur[17] = (fj + Cc[17]) + P4.y;
              cur[18] = (fj + Cc[18]) + P4.z; cur[19] = (fj + Cc[19]) + P4.w;
              cur[20] = (fj + Cc[20]) + P5.x; cur[21] = (fj + Cc[21]) + P5.y;
              cur[22] = (fj + Cc[22]) + P5.z; cur[23] = (fj + Cc[23]) + P5.w;
              cur[24] = (fj + Cc[24]) + P6.x; cur[25] = (fj + Cc[25]) + P6.y;
              cur[26] = (fj + Cc[26]) + P6.z; cur[27] = (fj + Cc[27]) + P6.w;
              cur[28] = (fj + Cc[28]) + P7.x; cur[29] = (fj + Cc[29]) + P7.y;
              cur[30] = (fj + Cc[30]) + P7.z; cur[31] = (fj + Cc[31]) + P7.w;
              float t0 = max3f(cur[0], cur[1], cur[2]);
              float t1 = max3f(cur[3], cur[4], cur[5]);
              float t2 = max3f(cur[6], cur[7], cur[8]);
              float t3 = max3f(cur[9], cur[10], cur[11]);
              float t4 = max3f(cur[12], cur[13], cur[14]);
              float t5 = max3f(cur[15], cur[16], cur[17]);
              float t6 = max3f(cur[18], cur[19], cur[20]);
              float t7 = max3f(cur[21], cur[22], cur[23]);
              float t8 = max3f(cur[24], cur[25], cur[26]);
              float t9 = max3f(cur[27], cur[28], cur[29]);
              float ta = fmaxf(cur[30], cur[31]);
              float vmax = fmaxf(fmaxf(max3f(t0, t1, t2), max3f(t3, t4, t5)),
                                 fmaxf(max3f(t6, t7, t8), fmaxf(t9, ta)));
              int bi = 31;
              unrollN<TT>([&](auto I) { constexpr int ii = 31 - I; bi = (cur[ii] == vmax) ? ii : bi; });
              bv = (unsigned char)bi;
            }
            bp[k * TT + jj] = bv;
          }
        });
      }
    }
    __syncthreads();

    // ---- chunked-hypothesis backtrace
    if (lane < 32) {
      const int lo = wave * 64;
      const int hi = (lo + 64 < KSTEPS) ? (lo + 64) : KSTEPS;
      int ptr = lane;
      for (int k = hi - 1; k >= lo; --k) {
        ptr = bp[k * TT + ptr];
        path[k * TT + lane] = (unsigned char)ptr;
      }
    }
    __syncthreads();

    if (tid == 0) {
      int e = ws_ptr[b];
      for (int c = 7; c >= 0; --c) {
        entries[c] = e;
        e = path[(c * 64) * TT + e];
      }
    }
    __syncthreads();

    const int s = tid;
    int val;
    if (s == 0) val = 0;
    else if (s <= KSTEPS) { int k = s - 1; val = path[k * TT + entries[k >> 6]]; }
    else val = ws_ptr[b];
    out_decode[(size_t)b * SS + s] = (float)val;

    // ---- loss (block for b==0 waits for all fwd + gold producers)
    if (b == 0) {
      __syncthreads();
      if (tid == 0) {
        while (atomicAdd(cntp, 0) < 512) __builtin_amdgcn_s_sleep(10);
      }
      __syncthreads();
      __threadfence();
      if (tid < 64) {
        int t = tid;
        float sf = 0.0f, sg = 0.0f;
        for (int r = 0; r < 4; ++r) { sf += ws_fwd[t + 64 * r]; sg += ws_gold[t + 64 * r]; }
        for (int d = 1; d < 64; d <<= 1) { sf += __shfl_xor(sf, d, 64); sg += __shfl_xor(sg, d, 64); }
        if (t == 0) out[0] = (sf - sg) / 256.0f;
      }
    }
  }
}

extern "C" void kernel_launch(void* const* d_in, const int* in_sizes, int n_in,
                              void* d_out, int out_size, void* d_ws, size_t ws_size,
                              hipStream_t stream) {
  const float* feats = (const float*)d_in[0];
  const float* trans = (const float*)d_in[1];
  const void* mask = d_in[2];
  const int* tags = (const int*)d_in[3];
  float* out = (float*)d_out;

  unsigned char* ws = (unsigned char*)d_ws;
  const size_t PST_BYTES = (size_t)NB * PQUADS * 128 * 4;  // 16,777,216
  float* pstore = (float*)ws;
  float* ws_fwd = (float*)(ws + PST_BYTES);
  float* ws_gold = (float*)(ws + PST_BYTES + 2048);
  int* ws_ptr = (int*)(ws + PST_BYTES + 4096);
  int* flags = (int*)(ws + PST_BYTES + 8192);          // 256 ints
  int* cntp = (int*)(ws + PST_BYTES + 8192 + 1024);    // 1 int

  hipMemsetAsync(ws + PST_BYTES + 8192, 0, 2048, stream);
  hipLaunchKernelGGL(crf_fused_kernel, dim3(BT_BASE + NB), dim3(512), 0, stream,
                     feats, trans, mask, tags, pstore, ws_fwd, ws_gold, ws_ptr,
                     flags, cntp, out);
}

// Round 18
// 100.232 us; speedup vs baseline: 1.7944x; 1.7944x over previous
//
#include <hip/hip_runtime.h>
#include <cstdint>
#include <cstddef>
#include <utility>

#define SS 512
#define TT 32
#define NB 256
#define KSTEPS 510   // SS-2
#define PQUADS 128   // pstore quads per batch (4 rows each)

// ---------- unroll helper (compile-time indices -> registers) ----------
template <typename F, size_t... Is>
__device__ __forceinline__ void unroll_impl(F&& f, std::index_sequence<Is...>) {
  (f(std::integral_constant<int, (int)Is>{}), ...);
}
template <int N, typename F>
__device__ __forceinline__ void unrollN(F&& f) {
  unroll_impl(f, std::make_index_sequence<N>{});
}

// butterfly xor D within each 32-lane group (one-time reductions only)
template <int D>
__device__ __forceinline__ float bfly32(float v) {
  return __int_as_float(__builtin_amdgcn_ds_swizzle(__float_as_int(v), (D << 10) | 0x1f));
}
template <int D>
__device__ __forceinline__ int bfly32i(int v) {
  return __builtin_amdgcn_ds_swizzle(v, (D << 10) | 0x1f);
}

__device__ __forceinline__ float max3f(float a, float b, float c) {
  return fmaxf(fmaxf(a, b), c);  // fuses to v_max3_f32; fmax exact in any grouping
}

// ---- DPP row rotate (16-lane row), compile-time amount R in [1,15] ----
template <int R>
__device__ __forceinline__ float dpp_rorf(float v) {
  return __int_as_float(__builtin_amdgcn_update_dpp(
      0, __float_as_int(v), 0x120 + R, 0xf, 0xf, true));  // row_ror:R
}
template <int R>
__device__ __forceinline__ int dpp_rori(int v) {
  return __builtin_amdgcn_update_dpp(0, v, 0x120 + R, 0xf, 0xf, true);
}

// ---- cross-lane pair combines, orientation-proof (r14-verified trick):
// passing the SAME value as both operands returns, per lane, the pair
// {own, partner} in SOME order -> max/sum/partner-extract are convention-free.
__device__ __forceinline__ float combine_max32(float m) {
#if __has_builtin(__builtin_amdgcn_permlane32_swap)
  auto r = __builtin_amdgcn_permlane32_swap(__float_as_uint(m), __float_as_uint(m), false, false);
  return fmaxf(__uint_as_float(r[0]), __uint_as_float(r[1]));
#else
  return fmaxf(m, __shfl_xor(m, 32, 64));
#endif
}
__device__ __forceinline__ float combine_sum32(float m) {
#if __has_builtin(__builtin_amdgcn_permlane32_swap)
  auto r = __builtin_amdgcn_permlane32_swap(__float_as_uint(m), __float_as_uint(m), false, false);
  return __uint_as_float(r[0]) + __uint_as_float(r[1]);
#else
  return m + __shfl_xor(m, 32, 64);
#endif
}
// value held by lane l^16 (row partner). partner = (r0==own) ? r1 : r0 is
// exact even on equality (then both are the same value).
__device__ __forceinline__ float partner16(float v) {
#if __has_builtin(__builtin_amdgcn_permlane16_swap)
  auto r = __builtin_amdgcn_permlane16_swap(__float_as_uint(v), __float_as_uint(v), false, false);
  float a = __uint_as_float(r[0]), b = __uint_as_float(r[1]);
  return (__float_as_uint(a) == __float_as_uint(v)) ? b : a;
#else
  return __shfl_xor(v, 16, 64);
#endif
}

// ---------- mask dtype autodetect (bool may arrive as i32 / u8 / f32) ----------
__device__ __forceinline__ int mask_mode(const void* m) {
  int w0 = ((const int*)m)[0];
  if (w0 == 1) return 0;                // int32 0/1
  if (w0 == 0x3f800000) return 2;       // float32 1.0
  return 1;                             // uint8
}
__device__ __forceinline__ bool mask_at(const void* m, int idx, int mode) {
  if (mode == 0) return ((const int*)m)[idx] != 0;
  if (mode == 2) return ((const float*)m)[idx] != 0.0f;
  return ((const unsigned char*)m)[idx] != 0;
}

// per-wave sequence length (lane in [0,64)); result uniform (SGPR)
__device__ __forceinline__ int seq_length_lane(const void* mask, int b, int lane, int mode) {
  int cnt = 0;
  for (int s = lane; s < SS; s += 64) cnt += mask_at(mask, b * SS + s, mode) ? 1 : 0;
  for (int d = 1; d < 64; d <<= 1) cnt += __shfl_xor(cnt, d, 64);
  return __builtin_amdgcn_readfirstlane(cnt);
}

// ---------- K1: fused forward / viterbi / gold (role by blockIdx) ----------
// Register-resident recurrence, NO LDS: DPP row layout
//   row0 (l 0-15):  holds p[0..15],  out-tags 0-15,  sources 0-15
//   row1 (l16-31):  holds p[16..31], out-tags 16-31, sources 16-31
//   row2 (l32-47):  holds p[16..31], out-tags 0-15,  sources 16-31
//   row3 (l48-63):  holds p[0..15],  out-tags 16-31, sources 0-15
// row_ror delivers all 16 row-held sources; pair l^32 (same out-tag) combines
// via permlane32_swap; rows 2/3 re-acquire their HELD tag via permlane16.
// trans columns are indexed through a DPP lane-id probe -> correct under
// either rotate direction. Viterbi streams partition rows (lanes 0-31 hold
// p[tag=lane]) to pstore; K2 recomputes backpointers bit-exactly.
__global__ __launch_bounds__(64, 1) void crf_main_kernel(
    const float* __restrict__ feats, const float* __restrict__ trans,
    const void* __restrict__ mask, const int* __restrict__ tags,
    float* __restrict__ pstore, float* __restrict__ ws_fwd,
    float* __restrict__ ws_gold, int* __restrict__ ws_ptr) {
  const int blk = blockIdx.x;
  const int tid = threadIdx.x;
  const int mode = mask_mode(mask);
  const int lane = tid & 63;
  const int l15 = lane & 15;
  const int row = lane >> 4;
  const int heldB = (row == 1 || row == 2) ? 16 : 0;   // held-tag base
  const int outB  = (row == 1 || row == 3) ? 16 : 0;   // out-tag base
  const int heldtag = l15 + heldB;
  const int outtag  = l15 + outB;
  const bool lower = (lane < 32);

  // DPP rotation source probe: src15[r] = lane-in-row that row_ror:r delivers
  int src15[16];
  src15[0] = l15;
  unrollN<15>([&](auto RR) { constexpr int r = RR + 1; src15[r] = dpp_rori<r>(l15); });

  if (blk < NB) {
    // ========== FORWARD, exp-space: q' = exp(f) * (E^T q), exact 2^k rescale ==========
    const int b = blk;
    const int steps = seq_length_lane(mask, b, tid, mode) - 2;
    const float* fb = feats + (size_t)b * (SS * TT) + outtag;

    float E[16];  // E[r] = exp(trans[src-of-rotation-r][outtag])
    unrollN<16>([&](auto RR) {
      constexpr int r = RR;
      E[r] = __expf(trans[(src15[r] + heldB) * TT + outtag]);
    });

    float q = __expf(feats[(size_t)b * (SS * TT) + TT + heldtag]);  // held tag's q
    int Eacc = 0;
    float fA = fb[2 * TT], fB = fb[3 * TT], fC = fb[4 * TT];
    float ef = __expf(fA);

    auto fstep = [&](int k, bool resc) {
      int r5 = k + 5; r5 = (r5 < SS) ? r5 : (SS - 1);
      float fD = fb[r5 * TT];                      // prefetch depth-3 (off-chain)
      float efN = __expf(fB);                      // next step's exp (off-chain)
      float a0 = q * E[0], a1, a2, a3;
      a1 = dpp_rorf<1>(q) * E[1];
      a2 = dpp_rorf<2>(q) * E[2];
      a3 = dpp_rorf<3>(q) * E[3];
      a0 = fmaf(dpp_rorf<4>(q),  E[4],  a0);
      a1 = fmaf(dpp_rorf<5>(q),  E[5],  a1);
      a2 = fmaf(dpp_rorf<6>(q),  E[6],  a2);
      a3 = fmaf(dpp_rorf<7>(q),  E[7],  a3);
      a0 = fmaf(dpp_rorf<8>(q),  E[8],  a0);
      a1 = fmaf(dpp_rorf<9>(q),  E[9],  a1);
      a2 = fmaf(dpp_rorf<10>(q), E[10], a2);
      a3 = fmaf(dpp_rorf<11>(q), E[11], a3);
      a0 = fmaf(dpp_rorf<12>(q), E[12], a0);
      a1 = fmaf(dpp_rorf<13>(q), E[13], a1);
      a2 = fmaf(dpp_rorf<14>(q), E[14], a2);
      a3 = fmaf(dpp_rorf<15>(q), E[15], a3);
      float P = (a0 + a1) + (a2 + a3);             // own-half partial (out-tag)
      float val = ef * combine_sum32(P);           // new q[outtag]
      float par = partner16(val);                  // pair-tag's new q
      float qn = lower ? val : par;                // restore HELD-tag layout
      if (resc) {
        int qb = __builtin_amdgcn_readfirstlane(__float_as_int(qn));  // q[0]
        int e = (qb >> 23) & 0xff;
        Eacc += e - 127;
        qn *= __int_as_float((254 - e) << 23);     // exact power-of-two scale
      }
      q = qn;
      fA = fB; fB = fC; fC = fD; ef = efN;
    };

    int k = 0;
    for (; k + 4 <= steps; k += 4) {
      fstep(k, false); fstep(k + 1, false); fstep(k + 2, false); fstep(k + 3, true);
    }
    for (; k < steps; ++k) fstep(k, false);

    // forward score = log(sum_j q_j) + Eacc*ln2 (lanes 0-31 hold q[tag=lane])
    float s = q;
    unrollN<5>([&](auto D) { constexpr int d = 1 << D; s += bfly32<d>(s); });
    if (tid == 0) ws_fwd[b] = __logf(s) + (float)Eacc * 0.69314718056f;

  } else if (blk < 2 * NB) {
    // ================= VITERBI (max only; bp deferred to K2) =================
    const int b = blk - NB;
    const int steps = seq_length_lane(mask, b, tid, mode) - 2;
    const float* fb = feats + (size_t)b * (SS * TT) + outtag;
    float* pq = pstore + (size_t)b * (PQUADS * 128) + lane * 4;  // lanes<32 slot

    float C[16];  // C[r] = trans[src-of-rotation-r][outtag]
    unrollN<16>([&](auto RR) {
      constexpr int r = RR;
      C[r] = trans[(src15[r] + heldB) * TT + outtag];
    });

    float p = feats[(size_t)b * (SS * TT) + TT + heldtag];  // held tag's p
    float fA = fb[2 * TT], fB = fb[3 * TT], fC = fb[4 * TT];
    float h0 = p, h1 = 0.f, h2 = 0.f, h3 = 0.f;  // row history (lanes<32 valid)

    auto vstep = [&](int k, float& hslot) {
      int r5 = k + 5; r5 = (r5 < SS) ? r5 : (SS - 1);
      float fD = fb[r5 * TT];
      float dd[16];  // fl(f[outtag] + tr[src][outtag]) — reference inner order
      unrollN<16>([&](auto RR) { constexpr int r = RR; dd[r] = fA + C[r]; });
      float cur[16];  // fl(fl(f+tr) + p): add commutative -> bitwise exact
      cur[0] = p + dd[0];
      cur[1]  = dpp_rorf<1>(p)  + dd[1];
      cur[2]  = dpp_rorf<2>(p)  + dd[2];
      cur[3]  = dpp_rorf<3>(p)  + dd[3];
      cur[4]  = dpp_rorf<4>(p)  + dd[4];
      cur[5]  = dpp_rorf<5>(p)  + dd[5];
      cur[6]  = dpp_rorf<6>(p)  + dd[6];
      cur[7]  = dpp_rorf<7>(p)  + dd[7];
      cur[8]  = dpp_rorf<8>(p)  + dd[8];
      cur[9]  = dpp_rorf<9>(p)  + dd[9];
      cur[10] = dpp_rorf<10>(p) + dd[10];
      cur[11] = dpp_rorf<11>(p) + dd[11];
      cur[12] = dpp_rorf<12>(p) + dd[12];
      cur[13] = dpp_rorf<13>(p) + dd[13];
      cur[14] = dpp_rorf<14>(p) + dd[14];
      cur[15] = dpp_rorf<15>(p) + dd[15];
      float t0 = max3f(cur[0], cur[1], cur[2]);
      float t1 = max3f(cur[3], cur[4], cur[5]);
      float t2 = max3f(cur[6], cur[7], cur[8]);
      float t3 = max3f(cur[9], cur[10], cur[11]);
      float t4 = max3f(cur[12], cur[13], cur[14]);
      float m = fmaxf(max3f(t0, t1, t2), max3f(t3, t4, cur[15]));  // half partial
      float full = combine_max32(m);               // new p[outtag] (exact)
      float par = partner16(full);                 // pair-tag's new p
      float pw = lower ? full : par;               // restore HELD-tag layout
      p = pw;
      hslot = pw;                                  // lanes<32: p[tag=lane]
      fA = fB; fB = fC; fC = fD;
    };

    auto flush = [&](int quad) {
      if (lane < 32) {
        float4 v; v.x = h0; v.y = h1; v.z = h2; v.w = h3;
        *(float4*)(pq + quad * 128) = v;
      }
    };

    int k = 0;
    for (; k + 4 <= steps; k += 4) {
      vstep(k, h1);        // row k+1
      vstep(k + 1, h2);    // row k+2
      vstep(k + 2, h3);    // row k+3
      flush(k >> 2);       // rows k..k+3
      vstep(k + 3, h0);    // row k+4 (next quad slot 0)
    }
    if (k < steps) vstep(k, h1);
    if (k + 1 < steps) vstep(k + 1, h2);
    if (k + 2 < steps) vstep(k + 2, h3);
    flush(k >> 2);         // tail rows (K2 guards k < steps)

    // pointer = first-max argmax over tags (lanes 0-31 hold p[tag=lane])
    float v = p;
    int idx = lane & 31;
    unrollN<5>([&](auto D) {
      constexpr int d = 1 << D;
      float vo = bfly32<d>(v);
      int io = bfly32i<d>(idx);
      bool take = (vo > v) || ((vo == v) && (io < idx));
      v = take ? vo : v;
      idx = take ? io : idx;
    });
    if (tid == 0) ws_ptr[b] = idx;

  } else {
    // ================= GOLD SCORE =================
    const int b = blk - 2 * NB;
    float acc = 0.0f;
    for (int s = tid; s < SS; s += 64) {
      if (s == 0) continue;
      if (!mask_at(mask, b * SS + s, mode)) continue;
      int tg = tags[b * SS + s];
      if (tg == -100) tg = 0;
      float e = feats[((size_t)b * SS + s) * TT + tg];
      if (s >= 2) {
        int tp = tags[b * SS + s - 1];
        if (tp == -100) tp = 0;
        e += trans[tp * TT + tg];
      }
      acc += e;
    }
    for (int d = 1; d < 64; d <<= 1) acc += __shfl_xor(acc, d, 64);
    if (tid == 0) ws_gold[b] = acc;
  }
}

// ---------- K2: parallel bp recompute + chunked backtrace + finish ----------
__global__ __launch_bounds__(512) void crf_backtrace_kernel(
    const float* __restrict__ pstore, const float* __restrict__ feats,
    const float* __restrict__ trans, const void* __restrict__ mask,
    const int* __restrict__ ws_ptr, const float* __restrict__ ws_fwd,
    const float* __restrict__ ws_gold, float* __restrict__ out) {
  __shared__ unsigned char bp[KSTEPS * TT];         // 16320 B
  __shared__ unsigned char path[KSTEPS * TT];       // 16320 B
  __shared__ __align__(16) float pT[16][4][TT];     // 8 KB transpose staging
  __shared__ int entries[8];

  const int b = blockIdx.x;
  const int tid = threadIdx.x;
  const int mode = mask_mode(mask);
  const int lane = tid & 63;
  float* out_decode = out + 1 + NB;

  const int steps = seq_length_lane(mask, b, lane, mode) - 2;

  if (tid == 0) out[1 + b] = 0.0f;  // path_score = zeros(B)
  if (b == 0 && tid >= 64 && tid < 128) {
    int t = tid - 64;
    float sf = 0.0f, sg = 0.0f;
    for (int r = 0; r < 4; ++r) { sf += ws_fwd[t + 64 * r]; sg += ws_gold[t + 64 * r]; }
    for (int d = 1; d < 64; d <<= 1) { sf += __shfl_xor(sf, d, 64); sg += __shfl_xor(sg, d, 64); }
    if (t == 0) out[0] = (sf - sg) / 256.0f;
  }

  // ---- parallel bp recompute, quad-based (r15-verified)
  {
    const int jj = tid & 31;
    const int g = tid >> 5;
    float Cc[TT];
    unrollN<TT>([&](auto I) { constexpr int ii = I; Cc[ii] = trans[ii * TT + jj]; });
    const float* pb = pstore + (size_t)b * (PQUADS * 128);
    const float* fbb = feats + (size_t)b * (SS * TT);
    for (int q = g; q < PQUADS; q += 16) {
      float4 V = *(const float4*)(pb + q * 128 + jj * 4);  // coalesced 512B/group
      pT[g][0][jj] = V.x; pT[g][1][jj] = V.y; pT[g][2][jj] = V.z; pT[g][3][jj] = V.w;
      asm volatile("" ::: "memory");
      unrollN<4>([&](auto R) {
        constexpr int r = R;
        const int k = 4 * q + r;
        if (k < KSTEPS) {
          unsigned char bv = 0;
          if (k < steps) {
            const float4* pr = (const float4*)pT[g][r];   // uniform per group
            float4 P0 = pr[0], P1 = pr[1], P2 = pr[2], P3 = pr[3];
            float4 P4 = pr[4], P5 = pr[5], P6 = pr[6], P7 = pr[7];
            float fj = fbb[(k + 2) * TT + jj];
            float cur[TT];  // fl(fl(f+tr) + p): identical floats to K1's chain
            cur[0]  = (fj + Cc[0])  + P0.x; cur[1]  = (fj + Cc[1])  + P0.y;
            cur[2]  = (fj + Cc[2])  + P0.z; cur[3]  = (fj + Cc[3])  + P0.w;
            cur[4]  = (fj + Cc[4])  + P1.x; cur[5]  = (fj + Cc[5])  + P1.y;
            cur[6]  = (fj + Cc[6])  + P1.z; cur[7]  = (fj + Cc[7])  + P1.w;
            cur[8]  = (fj + Cc[8])  + P2.x; cur[9]  = (fj + Cc[9])  + P2.y;
            cur[10] = (fj + Cc[10]) + P2.z; cur[11] = (fj + Cc[11]) + P2.w;
            cur[12] = (fj + Cc[12]) + P3.x; cur[13] = (fj + Cc[13]) + P3.y;
            cur[14] = (fj + Cc[14]) + P3.z; cur[15] = (fj + Cc[15]) + P3.w;
            cur[16] = (fj + Cc[16]) + P4.x; cur[17] = (fj + Cc[17]) + P4.y;
            cur[18] = (fj + Cc[18]) + P4.z; cur[19] = (fj + Cc[19]) + P4.w;
            cur[20] = (fj + Cc[20]) + P5.x; cur[21] = (fj + Cc[21]) + P5.y;
            cur[22] = (fj + Cc[22]) + P5.z; cur[23] = (fj + Cc[23]) + P5.w;
            cur[24] = (fj + Cc[24]) + P6.x; cur[25] = (fj + Cc[25]) + P6.y;
            cur[26] = (fj + Cc[26]) + P6.z; cur[27] = (fj + Cc[27]) + P6.w;
            cur[28] = (fj + Cc[28]) + P7.x; cur[29] = (fj + Cc[29]) + P7.y;
            cur[30] = (fj + Cc[30]) + P7.z; cur[31] = (fj + Cc[31]) + P7.w;
            float t0 = max3f(cur[0], cur[1], cur[2]);
            float t1 = max3f(cur[3], cur[4], cur[5]);
            float t2 = max3f(cur[6], cur[7], cur[8]);
            float t3 = max3f(cur[9], cur[10], cur[11]);
            float t4 = max3f(cur[12], cur[13], cur[14]);
            float t5 = max3f(cur[15], cur[16], cur[17]);
            float t6 = max3f(cur[18], cur[19], cur[20]);
            float t7 = max3f(cur[21], cur[22], cur[23]);
            float t8 = max3f(cur[24], cur[25], cur[26]);
            float t9 = max3f(cur[27], cur[28], cur[29]);
            float ta = fmaxf(cur[30], cur[31]);
            float vmax = fmaxf(fmaxf(max3f(t0, t1, t2), max3f(t3, t4, t5)),
                               fmaxf(max3f(t6, t7, t8), fmaxf(t9, ta)));
            int bi = 31;  // first-max (descending overwrite-on-equal = jnp.argmax)
            unrollN<TT>([&](auto I) { constexpr int ii = 31 - I; bi = (cur[ii] == vmax) ? ii : bi; });
            bv = (unsigned char)bi;
          }
          bp[k * TT + jj] = bv;
        }
      });
    }
  }
  __syncthreads();

  // ---- chunked-hypothesis backtrace (each wave = one 64-step chunk)
  const int wave = tid >> 6;
  if (lane < 32) {
    const int lo = wave * 64;
    const int hi = (lo + 64 < KSTEPS) ? (lo + 64) : KSTEPS;
    int ptr = lane;
    for (int k = hi - 1; k >= lo; --k) {
      ptr = bp[k * TT + ptr];
      path[k * TT + lane] = (unsigned char)ptr;
    }
  }
  __syncthreads();

  // compose chunk entries from the top (chunk 7 enters with pointer)
  if (tid == 0) {
    int e = ws_ptr[b];
    for (int c = 7; c >= 0; --c) {
      entries[c] = e;
      e = path[(c * 64) * TT + e];
    }
  }
  __syncthreads();

  // decode row: [0, ptrs[0..509], pointer]
  const int s = tid;
  int val;
  if (s == 0) val = 0;
  else if (s <= KSTEPS) { int k = s - 1; val = path[k * TT + entries[k >> 6]]; }
  else val = ws_ptr[b];
  out_decode[(size_t)b * SS + s] = (float)val;
}

extern "C" void kernel_launch(void* const* d_in, const int* in_sizes, int n_in,
                              void* d_out, int out_size, void* d_ws, size_t ws_size,
                              hipStream_t stream) {
  const float* feats = (const float*)d_in[0];
  const float* trans = (const float*)d_in[1];
  const void* mask = d_in[2];
  const int* tags = (const int*)d_in[3];
  float* out = (float*)d_out;

  unsigned char* ws = (unsigned char*)d_ws;
  const size_t PST_BYTES = (size_t)NB * PQUADS * 128 * 4;  // 16,777,216
  float* pstore = (float*)ws;
  float* ws_fwd = (float*)(ws + PST_BYTES);
  float* ws_gold = (float*)(ws + PST_BYTES + 2048);
  int* ws_ptr = (int*)(ws + PST_BYTES + 4096);

  hipLaunchKernelGGL(crf_main_kernel, dim3(3 * NB), dim3(64), 0, stream,
                     feats, trans, mask, tags, pstore, ws_fwd, ws_gold, ws_ptr);
  hipLaunchKernelGGL(crf_backtrace_kernel, dim3(NB), dim3(512), 0, stream,
                     pstore, feats, trans, mask, ws_ptr, ws_fwd, ws_gold, out);
}